// Round 3
// baseline (3047.996 us; speedup 1.0000x reference)
//
#include <hip/hip_runtime.h>
#include <hip/hip_bf16.h>

#define C 64       // channels
#define NSLICE 8   // channel slices
#define SW 8       // channels per slice

// ---------------------------------------------------------------------------
// Fused MLP: h = relu(relu(x @ W1) @ W2), output in slice-major layout:
// h8[slice][node][8].  Block = 256 threads computes 64 rows x 64 cols.
// A kept row-major in LDS (no transpose stores -> no 4-way conflicts).
// ---------------------------------------------------------------------------
__launch_bounds__(256, 4)
__global__ void mlp_kernel(const float* __restrict__ x,
                           const float* __restrict__ W1,
                           const float* __restrict__ W2,
                           float* __restrict__ h8, int nN)
{
    // Aliased LDS phases: phase1 = As[64][36] + Bs[32][68]; phase2 = Hs[64][68] + Ws[64][68]
    __shared__ float smem[8704];
    float (*As)[36] = (float(*)[36])smem;            // 2304 floats
    float (*Bs)[68] = (float(*)[68])(smem + 2304);   // 2176 floats
    float (*Hs)[68] = (float(*)[68])smem;            // 4352 floats
    float (*Ws)[68] = (float(*)[68])(smem + 4352);   // 4352 floats

    const int t  = threadIdx.x;
    const int ty = t >> 4;          // 0..15 -> rows 4*ty..4*ty+3
    const int tx = t & 15;          // 0..15 -> cols 4*tx..4*tx+3
    const int row0 = blockIdx.x * 64;

    float acc[4][4] = {};

    for (int k0 = 0; k0 < 512; k0 += 32) {
        // A tile: 64 rows x 32 k = 512 float4, 2 per thread, row-major
        #pragma unroll
        for (int h = 0; h < 2; ++h) {
            int f = t + 256 * h;
            int r  = f >> 3;
            int lk = (f & 7) * 4;
            int grow = row0 + r;
            float4 v = make_float4(0.f, 0.f, 0.f, 0.f);
            if (grow < nN)
                v = *(const float4*)&x[(size_t)grow * 512 + k0 + lk];
            *(float4*)&As[r][lk] = v;
        }
        // B tile: 32 k x 64 cols = 512 float4, 2 per thread
        #pragma unroll
        for (int h = 0; h < 2; ++h) {
            int f = t + 256 * h;
            int kr = f >> 4;
            int c4 = (f & 15) * 4;
            *(float4*)&Bs[kr][c4] = *(const float4*)&W1[(size_t)(k0 + kr) * 64 + c4];
        }
        __syncthreads();

        for (int kk = 0; kk < 32; kk += 4) {
            float4 a[4], b[4];
            #pragma unroll
            for (int i = 0; i < 4; ++i) a[i] = *(float4*)&As[ty * 4 + i][kk];
            #pragma unroll
            for (int j = 0; j < 4; ++j) b[j] = *(float4*)&Bs[kk + j][tx * 4];
            #pragma unroll
            for (int i = 0; i < 4; ++i) {
                float bx[4] = {b[0].x, b[1].x, b[2].x, b[3].x};
                // acc[i][j] += sum_m a[i][m] * Bs[kk+m][tx*4+j]
                acc[i][0] += a[i].x * b[0].x + a[i].y * b[1].x + a[i].z * b[2].x + a[i].w * b[3].x;
                acc[i][1] += a[i].x * b[0].y + a[i].y * b[1].y + a[i].z * b[2].y + a[i].w * b[3].y;
                acc[i][2] += a[i].x * b[0].z + a[i].y * b[1].z + a[i].z * b[2].z + a[i].w * b[3].z;
                acc[i][3] += a[i].x * b[0].w + a[i].y * b[1].w + a[i].z * b[2].w + a[i].w * b[3].w;
                (void)bx;
            }
        }
        __syncthreads();
    }

    // phase 2: Hs aliases As/Bs — safe after the final __syncthreads above.
    #pragma unroll
    for (int i = 0; i < 4; ++i) {
        float4 o;
        o.x = acc[i][0] > 0.f ? acc[i][0] : 0.f;
        o.y = acc[i][1] > 0.f ? acc[i][1] : 0.f;
        o.z = acc[i][2] > 0.f ? acc[i][2] : 0.f;
        o.w = acc[i][3] > 0.f ? acc[i][3] : 0.f;
        *(float4*)&Hs[ty * 4 + i][tx * 4] = o;
    }
    // Ws load (64x64 = 1024 float4, 4 per thread)
    #pragma unroll
    for (int q = 0; q < 4; ++q) {
        int f = t + 256 * q;
        int kr = f >> 4;
        int c4 = (f & 15) * 4;
        *(float4*)&Ws[kr][c4] = *(const float4*)&W2[(size_t)kr * 64 + c4];
    }
    __syncthreads();

    float acc2[4][4] = {};
    for (int kk = 0; kk < 64; kk += 4) {
        float4 a[4], b[4];
        #pragma unroll
        for (int i = 0; i < 4; ++i) a[i] = *(float4*)&Hs[ty * 4 + i][kk];
        #pragma unroll
        for (int j = 0; j < 4; ++j) b[j] = *(float4*)&Ws[kk + j][tx * 4];
        #pragma unroll
        for (int i = 0; i < 4; ++i) {
            acc2[i][0] += a[i].x * b[0].x + a[i].y * b[1].x + a[i].z * b[2].x + a[i].w * b[3].x;
            acc2[i][1] += a[i].x * b[0].y + a[i].y * b[1].y + a[i].z * b[2].y + a[i].w * b[3].y;
            acc2[i][2] += a[i].x * b[0].z + a[i].y * b[1].z + a[i].z * b[2].z + a[i].w * b[3].z;
            acc2[i][3] += a[i].x * b[0].w + a[i].y * b[1].w + a[i].z * b[2].w + a[i].w * b[3].w;
        }
    }

    // relu + slice-major store: col c=4tx+j -> slice tx>>1, offset (tx&1)*4+j
    const int slice = tx >> 1;
    const int soff  = (tx & 1) * 4;
    #pragma unroll
    for (int i = 0; i < 4; ++i) {
        int grow = row0 + ty * 4 + i;
        if (grow < nN) {
            float4 o;
            o.x = acc2[i][0] > 0.f ? acc2[i][0] : 0.f;
            o.y = acc2[i][1] > 0.f ? acc2[i][1] : 0.f;
            o.z = acc2[i][2] > 0.f ? acc2[i][2] : 0.f;
            o.w = acc2[i][3] > 0.f ? acc2[i][3] : 0.f;
            *(float4*)&h8[((size_t)slice * nN + grow) * SW + soff] = o;
        }
    }
}

// ---------------------------------------------------------------------------
// CSR build: degree count -> single-block scan -> atomic fill (packed col+wgt).
// After fill, rowptr[n] = END offset of node n; start = rowptr[n-1] (0 for n=0).
// ---------------------------------------------------------------------------
__launch_bounds__(256)
__global__ void count_kernel(const int* __restrict__ dst, int* __restrict__ rowptr, int nE)
{
    int e = blockIdx.x * 256 + threadIdx.x;
    if (e < nE) atomicAdd(&rowptr[dst[e]], 1);
}

__launch_bounds__(1024)
__global__ void scan_kernel(int* __restrict__ deg, int nN)
{
    __shared__ int sums[1024];
    const int t = threadIdx.x;
    const int len = (nN + 1023) / 1024;
    const int lo = t * len;
    const int hi = min(nN, lo + len);
    int s = 0;
    for (int i = lo; i < hi; ++i) s += deg[i];
    sums[t] = s;
    __syncthreads();
    for (int d = 1; d < 1024; d <<= 1) {
        int v = (t >= d) ? sums[t - d] : 0;
        __syncthreads();
        sums[t] += v;
        __syncthreads();
    }
    int off = sums[t] - s;
    for (int i = lo; i < hi; ++i) {
        int d = deg[i];
        deg[i] = off;
        off += d;
    }
}

__launch_bounds__(256)
__global__ void fill_kernel(const int* __restrict__ src, const int* __restrict__ dst,
                            const float* __restrict__ w,
                            int* __restrict__ rowptr,
                            int2* __restrict__ cwp, int nE)
{
    int e = blockIdx.x * 256 + threadIdx.x;
    if (e >= nE) return;
    int d = dst[e];
    int pos = atomicAdd(&rowptr[d], 1);
    cwp[pos] = make_int2(src[e], __float_as_int(w[e]));
}

// ---------------------------------------------------------------------------
// Channel-sliced pull SpMM. One slice (nN x 8ch, 3.2 MB) fits per-XCD L2.
// Grid = (node_blocks, NSLICE); x-major dispatch keeps one slice hot at a time.
// Lane layout: 8 nodes/wave x 8 channels. col+wgt broadcast via one int2 load.
// ---------------------------------------------------------------------------
__launch_bounds__(256)
__global__ void spmm_slice(const int* __restrict__ rowptr,
                           const int2* __restrict__ cwp,
                           const float* __restrict__ cur8,
                           float* __restrict__ nxt8, int nN)
{
    const int slice = blockIdx.y;
    const float* __restrict__ cur = cur8 + (size_t)slice * nN * SW;
    float* __restrict__ nxt = nxt8 + (size_t)slice * nN * SW;

    int t = threadIdx.x;
    int node = blockIdx.x * 32 + (t >> 3);
    if (node >= nN) return;
    int c = t & 7;

    int beg = (node == 0) ? 0 : rowptr[node - 1];
    int end = rowptr[node];

    float a0 = 0.f, a1 = 0.f;
    int e = beg;
    for (; e + 1 < end; e += 2) {
        int2 cw0 = cwp[e];
        int2 cw1 = cwp[e + 1];
        a0 += __int_as_float(cw0.y) * cur[(size_t)cw0.x * SW + c];
        a1 += __int_as_float(cw1.y) * cur[(size_t)cw1.x * SW + c];
    }
    if (e < end) {
        int2 cw0 = cwp[e];
        a0 += __int_as_float(cw0.y) * cur[(size_t)cw0.x * SW + c];
    }
    nxt[(size_t)node * SW + c] = a0 + a1;
}

// ---------------------------------------------------------------------------
// Gate-gather from slice-major h: out[i] (+)= sigmoid(h[idx[i]].wp) * h[idx[i]]
// ---------------------------------------------------------------------------
__launch_bounds__(256)
__global__ void gate_gather(const float* __restrict__ h8,
                            const int* __restrict__ idx,
                            const float* __restrict__ wp,
                            float* __restrict__ out, int nN, int nI, int init)
{
    int gid = blockIdx.x * 256 + threadIdx.x;
    int i = gid >> 6;
    if (i >= nI) return;
    int c = gid & 63;
    int n = idx[i];
    float v = h8[((size_t)(c >> 3) * nN + n) * SW + (c & 7)];
    float s = v * wp[c];
    #pragma unroll
    for (int off = 32; off > 0; off >>= 1)
        s += __shfl_xor(s, off);
    float gate = 1.f / (1.f + __expf(-s));
    float o = gate * v;
    if (init) out[gid] = o;
    else      out[gid] += o;
}

extern "C" void kernel_launch(void* const* d_in, const int* in_sizes, int n_in,
                              void* d_out, int out_size, void* d_ws, size_t ws_size,
                              hipStream_t stream) {
    const float* x    = (const float*)d_in[0];
    const int*   esrc = (const int*)d_in[1];
    const int*   edst = (const int*)d_in[2];
    const float* ew   = (const float*)d_in[3];
    const int*   nidx = (const int*)d_in[4];
    const float* W1   = (const float*)d_in[5];
    const float* W2   = (const float*)d_in[6];
    const float* wp   = (const float*)d_in[7];
    float* out = (float*)d_out;

    const int nN = in_sizes[0] / 512;
    const int nE = in_sizes[1];
    const int nI = in_sizes[4];

    // ws layout: bufA 25.6M | bufB 25.6M | rowptr 0.4M | cwp 12.8M  (= 64.4 MB)
    float* bufA   = (float*)d_ws;
    float* bufB   = bufA + (size_t)nN * C;
    int*   rowptr = (int*)(bufB + (size_t)nN * C);
    int2*  cwp    = (int2*)(rowptr + nN);

    // --- CSR build (by dst) ---
    hipMemsetAsync(rowptr, 0, (size_t)nN * sizeof(int), stream);
    count_kernel<<<(nE + 255) / 256, 256, 0, stream>>>(edst, rowptr, nE);
    scan_kernel<<<1, 1024, 0, stream>>>(rowptr, nN);
    fill_kernel<<<(nE + 255) / 256, 256, 0, stream>>>(esrc, edst, ew, rowptr, cwp, nE);

    // --- MLP (writes slice-major) ---
    mlp_kernel<<<(nN + 63) / 64, 256, 0, stream>>>(x, W1, W2, bufA, nN);

    // hop 0 gate directly into out
    gate_gather<<<(nI * 64 + 255) / 256, 256, 0, stream>>>(bufA, nidx, wp, out, nN, nI, 1);

    float* cur = bufA;
    float* nxt = bufB;
    dim3 sgrid((nN + 31) / 32, NSLICE);
    for (int k = 0; k < 10; ++k) {
        spmm_slice<<<sgrid, 256, 0, stream>>>(rowptr, cwp, cur, nxt, nN);
        gate_gather<<<(nI * 64 + 255) / 256, 256, 0, stream>>>(nxt, nidx, wp, out, nN, nI, 0);
        float* tmp = cur; cur = nxt; nxt = tmp;
    }
}

// Round 4
// 1386.283 us; speedup vs baseline: 2.1987x; 2.1987x over previous
//
#include <hip/hip_runtime.h>
#include <hip/hip_bf16.h>

#define C 64  // channels

// ---------------------------------------------------------------------------
// Fused MLP: h0 = relu(relu(x @ W1) @ W2), output row-major [nN][64].
// Block = 256 threads computes 64 rows x 64 cols; 4x4 microtile per thread.
// A kept row-major in LDS (float4 reads along k -> no transpose-store conflicts).
// No min-wave launch_bounds: let the allocator keep ~120 VGPRs, zero spills.
// ---------------------------------------------------------------------------
__launch_bounds__(256)
__global__ void mlp_kernel(const float* __restrict__ x,
                           const float* __restrict__ W1,
                           const float* __restrict__ W2,
                           float* __restrict__ h0, int nN)
{
    // Aliased LDS phases: phase1 = As[64][36] + Bs[32][68]; phase2 = Hs[64][68] + Ws[64][68]
    __shared__ float smem[8704];
    float (*As)[36] = (float(*)[36])smem;            // 2304 floats
    float (*Bs)[68] = (float(*)[68])(smem + 2304);   // 2176 floats
    float (*Hs)[68] = (float(*)[68])smem;            // 4352 floats
    float (*Ws)[68] = (float(*)[68])(smem + 4352);   // 4352 floats

    const int t  = threadIdx.x;
    const int ty = t >> 4;          // 0..15 -> rows 4*ty..4*ty+3
    const int tx = t & 15;          // 0..15 -> cols 4*tx..4*tx+3
    const int row0 = blockIdx.x * 64;

    float acc[4][4] = {};

    for (int k0 = 0; k0 < 512; k0 += 32) {
        // A tile: 64 rows x 32 k = 512 float4, 2 per thread, row-major
        #pragma unroll
        for (int h = 0; h < 2; ++h) {
            int f = t + 256 * h;
            int r  = f >> 3;
            int lk = (f & 7) * 4;
            int grow = row0 + r;
            float4 v = make_float4(0.f, 0.f, 0.f, 0.f);
            if (grow < nN)
                v = *(const float4*)&x[(size_t)grow * 512 + k0 + lk];
            *(float4*)&As[r][lk] = v;
        }
        // B tile: 32 k x 64 cols = 512 float4, 2 per thread
        #pragma unroll
        for (int h = 0; h < 2; ++h) {
            int f = t + 256 * h;
            int kr = f >> 4;
            int c4 = (f & 15) * 4;
            *(float4*)&Bs[kr][c4] = *(const float4*)&W1[(size_t)(k0 + kr) * 64 + c4];
        }
        __syncthreads();

        for (int kk = 0; kk < 32; kk += 4) {
            float4 b0 = *(float4*)&Bs[kk + 0][tx * 4];
            float4 b1 = *(float4*)&Bs[kk + 1][tx * 4];
            float4 b2 = *(float4*)&Bs[kk + 2][tx * 4];
            float4 b3 = *(float4*)&Bs[kk + 3][tx * 4];
            #pragma unroll
            for (int i = 0; i < 4; ++i) {
                float4 a = *(float4*)&As[ty * 4 + i][kk];
                acc[i][0] += a.x * b0.x + a.y * b1.x + a.z * b2.x + a.w * b3.x;
                acc[i][1] += a.x * b0.y + a.y * b1.y + a.z * b2.y + a.w * b3.y;
                acc[i][2] += a.x * b0.z + a.y * b1.z + a.z * b2.z + a.w * b3.z;
                acc[i][3] += a.x * b0.w + a.y * b1.w + a.z * b2.w + a.w * b3.w;
            }
        }
        __syncthreads();
    }

    // phase 2: Hs aliases As/Bs — safe after the final __syncthreads above.
    #pragma unroll
    for (int i = 0; i < 4; ++i) {
        float4 o;
        o.x = acc[i][0] > 0.f ? acc[i][0] : 0.f;
        o.y = acc[i][1] > 0.f ? acc[i][1] : 0.f;
        o.z = acc[i][2] > 0.f ? acc[i][2] : 0.f;
        o.w = acc[i][3] > 0.f ? acc[i][3] : 0.f;
        *(float4*)&Hs[ty * 4 + i][tx * 4] = o;
    }
    // Ws load (64x64 = 1024 float4, 4 per thread)
    #pragma unroll
    for (int q = 0; q < 4; ++q) {
        int f = t + 256 * q;
        int kr = f >> 4;
        int c4 = (f & 15) * 4;
        *(float4*)&Ws[kr][c4] = *(const float4*)&W2[(size_t)kr * 64 + c4];
    }
    __syncthreads();

    float acc2[4][4] = {};
    for (int kk = 0; kk < 64; kk += 4) {
        float4 b0 = *(float4*)&Ws[kk + 0][tx * 4];
        float4 b1 = *(float4*)&Ws[kk + 1][tx * 4];
        float4 b2 = *(float4*)&Ws[kk + 2][tx * 4];
        float4 b3 = *(float4*)&Ws[kk + 3][tx * 4];
        #pragma unroll
        for (int i = 0; i < 4; ++i) {
            float4 a = *(float4*)&Hs[ty * 4 + i][kk];
            acc2[i][0] += a.x * b0.x + a.y * b1.x + a.z * b2.x + a.w * b3.x;
            acc2[i][1] += a.x * b0.y + a.y * b1.y + a.z * b2.y + a.w * b3.y;
            acc2[i][2] += a.x * b0.z + a.y * b1.z + a.z * b2.z + a.w * b3.z;
            acc2[i][3] += a.x * b0.w + a.y * b1.w + a.z * b2.w + a.w * b3.w;
        }
    }

    // relu + row-major write
    #pragma unroll
    for (int i = 0; i < 4; ++i) {
        int grow = row0 + ty * 4 + i;
        if (grow < nN) {
            float4 o;
            o.x = acc2[i][0] > 0.f ? acc2[i][0] : 0.f;
            o.y = acc2[i][1] > 0.f ? acc2[i][1] : 0.f;
            o.z = acc2[i][2] > 0.f ? acc2[i][2] : 0.f;
            o.w = acc2[i][3] > 0.f ? acc2[i][3] : 0.f;
            *(float4*)&h0[(size_t)grow * 64 + tx * 4] = o;
        }
    }
}

// ---------------------------------------------------------------------------
// CSR build: degree count -> single-block scan -> atomic fill (packed col+wgt).
// After fill, rowptr[n] = END offset of node n; start = rowptr[n-1] (0 for n=0).
// ---------------------------------------------------------------------------
__launch_bounds__(256)
__global__ void count_kernel(const int* __restrict__ dst, int* __restrict__ rowptr, int nE)
{
    int e = blockIdx.x * 256 + threadIdx.x;
    if (e < nE) atomicAdd(&rowptr[dst[e]], 1);
}

__launch_bounds__(1024)
__global__ void scan_kernel(int* __restrict__ deg, int nN)
{
    __shared__ int sums[1024];
    const int t = threadIdx.x;
    const int len = (nN + 1023) / 1024;
    const int lo = t * len;
    const int hi = min(nN, lo + len);
    int s = 0;
    for (int i = lo; i < hi; ++i) s += deg[i];
    sums[t] = s;
    __syncthreads();
    for (int d = 1; d < 1024; d <<= 1) {
        int v = (t >= d) ? sums[t - d] : 0;
        __syncthreads();
        sums[t] += v;
        __syncthreads();
    }
    int off = sums[t] - s;
    for (int i = lo; i < hi; ++i) {
        int d = deg[i];
        deg[i] = off;
        off += d;
    }
}

__launch_bounds__(256)
__global__ void fill_kernel(const int* __restrict__ src, const int* __restrict__ dst,
                            const float* __restrict__ w,
                            int* __restrict__ rowptr,
                            int2* __restrict__ cwp, int nE)
{
    int e = blockIdx.x * 256 + threadIdx.x;
    if (e >= nE) return;
    int d = dst[e];
    int pos = atomicAdd(&rowptr[d], 1);
    cwp[pos] = make_int2(src[e], __float_as_int(w[e]));
}

// ---------------------------------------------------------------------------
// Pull-mode SpMM: one wave per dst node, h row-major [nN][64].
// 4 edge groups x 16 lanes (float4 each); 2 edges unrolled per group
// (8 edges in flight per wave). Single broadcast int2 load per edge.
// ---------------------------------------------------------------------------
__launch_bounds__(256)
__global__ void spmm_pull(const int* __restrict__ rowptr,
                          const int2* __restrict__ cwp,
                          const float* __restrict__ cur,
                          float* __restrict__ nxt, int nN)
{
    int gid = blockIdx.x * 256 + threadIdx.x;
    int node = gid >> 6;
    if (node >= nN) return;
    int lane = threadIdx.x & 63;
    int g = lane >> 4;   // edge sub-slot 0..3
    int q = lane & 15;   // channel quad

    int beg = (node == 0) ? 0 : rowptr[node - 1];
    int end = rowptr[node];

    float4 a0 = make_float4(0.f, 0.f, 0.f, 0.f);
    float4 a1 = make_float4(0.f, 0.f, 0.f, 0.f);
    int e = beg + g;
    for (; e + 4 < end; e += 8) {
        int2 cw0 = cwp[e];
        int2 cw1 = cwp[e + 4];
        float4 v0 = *(const float4*)&cur[(size_t)cw0.x * 64 + q * 4];
        float4 v1 = *(const float4*)&cur[(size_t)cw1.x * 64 + q * 4];
        float w0 = __int_as_float(cw0.y);
        float w1 = __int_as_float(cw1.y);
        a0.x += w0 * v0.x; a0.y += w0 * v0.y; a0.z += w0 * v0.z; a0.w += w0 * v0.w;
        a1.x += w1 * v1.x; a1.y += w1 * v1.y; a1.z += w1 * v1.z; a1.w += w1 * v1.w;
    }
    if (e < end) {
        int2 cw0 = cwp[e];
        float4 v0 = *(const float4*)&cur[(size_t)cw0.x * 64 + q * 4];
        float w0 = __int_as_float(cw0.y);
        a0.x += w0 * v0.x; a0.y += w0 * v0.y; a0.z += w0 * v0.z; a0.w += w0 * v0.w;
    }
    a0.x += a1.x; a0.y += a1.y; a0.z += a1.z; a0.w += a1.w;

    // combine the 4 edge groups (lanes differing in bits 4,5)
    a0.x += __shfl_xor(a0.x, 16); a0.y += __shfl_xor(a0.y, 16);
    a0.z += __shfl_xor(a0.z, 16); a0.w += __shfl_xor(a0.w, 16);
    a0.x += __shfl_xor(a0.x, 32); a0.y += __shfl_xor(a0.y, 32);
    a0.z += __shfl_xor(a0.z, 32); a0.w += __shfl_xor(a0.w, 32);

    if (g == 0)
        *(float4*)&nxt[(size_t)node * 64 + q * 4] = a0;
}

// ---------------------------------------------------------------------------
// Gate-gather: out[i] (+)= sigmoid(h[idx[i]].wp) * h[idx[i]], h row-major.
// ---------------------------------------------------------------------------
__launch_bounds__(256)
__global__ void gate_gather(const float* __restrict__ h,
                            const int* __restrict__ idx,
                            const float* __restrict__ wp,
                            float* __restrict__ out, int nI, int init)
{
    int gid = blockIdx.x * 256 + threadIdx.x;
    int i = gid >> 6;
    if (i >= nI) return;
    int c = gid & 63;
    int n = idx[i];
    float v = h[(size_t)n * 64 + c];
    float s = v * wp[c];
    #pragma unroll
    for (int off = 32; off > 0; off >>= 1)
        s += __shfl_xor(s, off);
    float gate = 1.f / (1.f + __expf(-s));
    float o = gate * v;
    if (init) out[gid] = o;
    else      out[gid] += o;
}

extern "C" void kernel_launch(void* const* d_in, const int* in_sizes, int n_in,
                              void* d_out, int out_size, void* d_ws, size_t ws_size,
                              hipStream_t stream) {
    const float* x    = (const float*)d_in[0];
    const int*   esrc = (const int*)d_in[1];
    const int*   edst = (const int*)d_in[2];
    const float* ew   = (const float*)d_in[3];
    const int*   nidx = (const int*)d_in[4];
    const float* W1   = (const float*)d_in[5];
    const float* W2   = (const float*)d_in[6];
    const float* wp   = (const float*)d_in[7];
    float* out = (float*)d_out;

    const int nN = in_sizes[0] / 512;
    const int nE = in_sizes[1];
    const int nI = in_sizes[4];

    // ws layout: bufA 25.6M | bufB 25.6M | rowptr 0.4M | cwp 12.8M  (= 64.4 MB)
    float* bufA   = (float*)d_ws;
    float* bufB   = bufA + (size_t)nN * C;
    int*   rowptr = (int*)(bufB + (size_t)nN * C);
    int2*  cwp    = (int2*)(rowptr + nN);

    // --- CSR build (by dst) ---
    hipMemsetAsync(rowptr, 0, (size_t)nN * sizeof(int), stream);
    count_kernel<<<(nE + 255) / 256, 256, 0, stream>>>(edst, rowptr, nE);
    scan_kernel<<<1, 1024, 0, stream>>>(rowptr, nN);
    fill_kernel<<<(nE + 255) / 256, 256, 0, stream>>>(esrc, edst, ew, rowptr, cwp, nE);

    // --- MLP (row-major h) ---
    mlp_kernel<<<(nN + 63) / 64, 256, 0, stream>>>(x, W1, W2, bufA, nN);

    // hop 0 gate directly into out
    gate_gather<<<(nI * 64 + 255) / 256, 256, 0, stream>>>(bufA, nidx, wp, out, nI, 1);

    float* cur = bufA;
    float* nxt = bufB;
    for (int k = 0; k < 10; ++k) {
        spmm_pull<<<((size_t)nN * 64 + 255) / 256, 256, 0, stream>>>(
            rowptr, cwp, cur, nxt, nN);
        gate_gather<<<(nI * 64 + 255) / 256, 256, 0, stream>>>(nxt, nidx, wp, out, nI, 0);
        float* tmp = cur; cur = nxt; nxt = tmp;
    }
}